// Round 1
// baseline (308.744 us; speedup 1.0000x reference)
//
#include <hip/hip_runtime.h>

typedef __bf16 bf16x8 __attribute__((ext_vector_type(8)));
typedef float floatx4 __attribute__((ext_vector_type(4)));

constexpr int Bc = 4, Hc = 8, Nc = 2048, Dc = 64;
constexpr int BQ = 64;   // q-rows per block
constexpr int WQ = 16;   // q-rows per wave
constexpr int TK = 32;   // keys per tile
constexpr int SKS = 72;  // sK row stride (bf16 elems) = 144 B (pad 8 -> 2-way-free banks)
constexpr int SVS = 40;  // sVt row stride = 80 B
constexpr int SPS = 40;  // sP row stride = 80 B

// logits = (2*q.k - kk_j)/sqrt(D), sqrt(D)=8. qq term cancels in softmax.
// Fold 2/8 into Q pre-scale (0.25, exact) and run softmax in exp2 domain.
__global__ __launch_bounds__(256) void attn_dist_kernel(
    const float* __restrict__ Qg, const float* __restrict__ Kg,
    const float* __restrict__ Vg, float* __restrict__ Og)
{
    __shared__ __bf16 sK[TK * SKS];        // K tile, row-major [key][d]
    __shared__ __bf16 sVt[Dc * SVS];       // V tile transposed [d][key]
    __shared__ __bf16 sP[4 * WQ * SPS];    // per-wave P round-trip [row][key]
    __shared__ float  skk[TK];

    const int tid  = threadIdx.x;
    const int wave = tid >> 6;
    const int lane = tid & 63;
    const int qd   = lane >> 4;   // quad 0..3
    const int c    = lane & 15;

    const int qt = blockIdx.x;    // 0..31 q-tiles
    const int bh = blockIdx.y;    // 0..31 (b*H + h)
    const size_t base = (size_t)bh * Nc * Dc;
    const float* Qp = Qg + base;
    const float* Kp = Kg + base;
    const float* Vp = Vg + base;

    constexpr float LOG2E = 1.44269504088896340736f;
    const float qscale  = 0.25f  * LOG2E;
    const float kkscale = 0.125f * LOG2E;

    const int i0w = qt * BQ + wave * WQ;

    // Q fragments in A-layout: m = c (row i0w+c), k(d) = ks*32 + qd*8 + jj
    bf16x8 qf[2];
    {
        const float* qrow = Qp + (size_t)(i0w + c) * Dc + qd * 8;
#pragma unroll
        for (int ks = 0; ks < 2; ++ks) {
            float4 a = *(const float4*)(qrow + ks * 32);
            float4 b = *(const float4*)(qrow + ks * 32 + 4);
            qf[ks][0] = (__bf16)(a.x * qscale);
            qf[ks][1] = (__bf16)(a.y * qscale);
            qf[ks][2] = (__bf16)(a.z * qscale);
            qf[ks][3] = (__bf16)(a.w * qscale);
            qf[ks][4] = (__bf16)(b.x * qscale);
            qf[ks][5] = (__bf16)(b.y * qscale);
            qf[ks][6] = (__bf16)(b.z * qscale);
            qf[ks][7] = (__bf16)(b.w * qscale);
        }
    }

    // Online-softmax state. C-layout rows owned by this lane: row = qd*4 + r.
    float mrow[4], lrow[4];
    floatx4 oacc[4];               // O in C-layout, 4 d-tiles of 16 cols
#pragma unroll
    for (int r = 0; r < 4; ++r) { mrow[r] = -__builtin_inff(); lrow[r] = 0.f; }
#pragma unroll
    for (int dt = 0; dt < 4; ++dt)
#pragma unroll
        for (int e = 0; e < 4; ++e) oacc[dt][e] = 0.f;

    const int jl = tid >> 3;        // 0..31: key row this thread stages
    const int dp = (tid & 7) * 8;   // 0..56: d-chunk this thread stages

    for (int jt = 0; jt < Nc / TK; ++jt) {
        __syncthreads();   // previous tile fully consumed
        {
            const float* kr = Kp + (size_t)(jt * TK + jl) * Dc + dp;
            float4 a = *(const float4*)kr;
            float4 b = *(const float4*)(kr + 4);
            // kk_j in fp32 from fp32 K (8-lane shuffle tree)
            float ss = a.x*a.x + a.y*a.y + a.z*a.z + a.w*a.w
                     + b.x*b.x + b.y*b.y + b.z*b.z + b.w*b.w;
            ss += __shfl_xor(ss, 1);
            ss += __shfl_xor(ss, 2);
            ss += __shfl_xor(ss, 4);
            if ((tid & 7) == 0) skk[jl] = ss * kkscale;
            bf16x8 kv;
            kv[0]=(__bf16)a.x; kv[1]=(__bf16)a.y; kv[2]=(__bf16)a.z; kv[3]=(__bf16)a.w;
            kv[4]=(__bf16)b.x; kv[5]=(__bf16)b.y; kv[6]=(__bf16)b.z; kv[7]=(__bf16)b.w;
            *(bf16x8*)(&sK[jl * SKS + dp]) = kv;   // 16B aligned store

            const float* vr = Vp + (size_t)(jt * TK + jl) * Dc + dp;
            float4 va = *(const float4*)vr;
            float4 vb = *(const float4*)(vr + 4);
            sVt[(dp + 0) * SVS + jl] = (__bf16)va.x;
            sVt[(dp + 1) * SVS + jl] = (__bf16)va.y;
            sVt[(dp + 2) * SVS + jl] = (__bf16)va.z;
            sVt[(dp + 3) * SVS + jl] = (__bf16)va.w;
            sVt[(dp + 4) * SVS + jl] = (__bf16)vb.x;
            sVt[(dp + 5) * SVS + jl] = (__bf16)vb.y;
            sVt[(dp + 6) * SVS + jl] = (__bf16)vb.z;
            sVt[(dp + 7) * SVS + jl] = (__bf16)vb.w;
        }
        __syncthreads();

        // S = (0.25*log2e*Q) . K^T   (two 16-col n-tiles, two K=32 d-steps)
        floatx4 s0 = {0.f, 0.f, 0.f, 0.f};
        floatx4 s1 = {0.f, 0.f, 0.f, 0.f};
#pragma unroll
        for (int ks = 0; ks < 2; ++ks) {
            bf16x8 k0 = *(const bf16x8*)(&sK[(c     ) * SKS + ks * 32 + qd * 8]);
            bf16x8 k1 = *(const bf16x8*)(&sK[(16 + c) * SKS + ks * 32 + qd * 8]);
            s0 = __builtin_amdgcn_mfma_f32_16x16x32_bf16(qf[ks], k0, s0, 0, 0, 0);
            s1 = __builtin_amdgcn_mfma_f32_16x16x32_bf16(qf[ks], k1, s1, 0, 0, 0);
        }
        const float kb0 = skk[c];
        const float kb1 = skk[16 + c];

        float p0[4], p1[4], alpha[4];
#pragma unroll
        for (int r = 0; r < 4; ++r) {
            float a0 = s0[r] - kb0;   // logit*log2e for key (jt*32 + c)
            float a1 = s1[r] - kb1;   // key (jt*32 + 16 + c)
            float t = fmaxf(a0, a1);
            t = fmaxf(t, __shfl_xor(t, 1));
            t = fmaxf(t, __shfl_xor(t, 2));
            t = fmaxf(t, __shfl_xor(t, 4));
            t = fmaxf(t, __shfl_xor(t, 8));
            float mnew = fmaxf(mrow[r], t);
            alpha[r] = __builtin_amdgcn_exp2f(mrow[r] - mnew);  // -inf -> 0
            mrow[r] = mnew;
            p0[r] = __builtin_amdgcn_exp2f(a0 - mnew);
            p1[r] = __builtin_amdgcn_exp2f(a1 - mnew);
            float rs = p0[r] + p1[r];
            rs += __shfl_xor(rs, 1);
            rs += __shfl_xor(rs, 2);
            rs += __shfl_xor(rs, 4);
            rs += __shfl_xor(rs, 8);
            lrow[r] = lrow[r] * alpha[r] + rs;
        }
#pragma unroll
        for (int dt = 0; dt < 4; ++dt)
#pragma unroll
            for (int r = 0; r < 4; ++r)
                oacc[dt][r] *= alpha[r];

        // P: C-layout -> A-layout via per-wave LDS round-trip (m120 pattern).
        // Same-wave ds write->read; compiler orders via lgkmcnt, no barrier.
        __bf16* sPw = &sP[wave * WQ * SPS];
#pragma unroll
        for (int r = 0; r < 4; ++r) {
            sPw[(qd * 4 + r) * SPS + c]      = (__bf16)p0[r];
            sPw[(qd * 4 + r) * SPS + 16 + c] = (__bf16)p1[r];
        }
        bf16x8 pf = *(const bf16x8*)(&sPw[c * SPS + qd * 8]);  // A-layout: m=c, k=qd*8+jj
#pragma unroll
        for (int dt = 0; dt < 4; ++dt) {
            bf16x8 vf = *(const bf16x8*)(&sVt[(dt * 16 + c) * SVS + qd * 8]);
            oacc[dt] = __builtin_amdgcn_mfma_f32_16x16x32_bf16(pf, vf, oacc[dt], 0, 0, 0);
        }
    }

    // Epilogue: out[b][i][h][d] = O[i][d] / l_i   (output is [B,N,H,D])
    const int b = bh >> 3;   // H = 8
    const int h = bh & 7;
#pragma unroll
    for (int r = 0; r < 4; ++r) {
        const float inv = 1.f / lrow[r];
        const int i = i0w + qd * 4 + r;
        float* orow = Og + (((size_t)b * Nc + i) * Hc + h) * Dc + c;
#pragma unroll
        for (int dt = 0; dt < 4; ++dt)
            orow[dt * 16] = oacc[dt][r] * inv;
    }
}

extern "C" void kernel_launch(void* const* d_in, const int* in_sizes, int n_in,
                              void* d_out, int out_size, void* d_ws, size_t ws_size,
                              hipStream_t stream) {
    const float* q = (const float*)d_in[0];
    const float* k = (const float*)d_in[1];
    const float* v = (const float*)d_in[2];
    float* out = (float*)d_out;
    dim3 grid(Nc / BQ, Bc * Hc);
    dim3 block(256);
    attn_dist_kernel<<<grid, block, 0, stream>>>(q, k, v, out);
}

// Round 2
// 147.563 us; speedup vs baseline: 2.0923x; 2.0923x over previous
//
#include <hip/hip_runtime.h>

typedef __bf16 bf16x4 __attribute__((ext_vector_type(4)));
typedef __bf16 bf16x8 __attribute__((ext_vector_type(8)));
typedef float floatx4 __attribute__((ext_vector_type(4)));

constexpr int Bc = 4, Hc = 8, Nc = 2048, Dc = 64;
constexpr int BQ = 128;  // q-rows per block
constexpr int WQ = 32;   // q-rows per wave (2 halves of 16)
constexpr int TK = 64;   // keys per tile
constexpr int SKS = 72;  // sK row stride (bf16), 144 B
constexpr int SPS = 72;  // sP row stride (bf16), 144 B

// logits*log2e = (2qk - kk)/8 * log2e; qq cancels in softmax. All work in
// exp2 domain, NO max-subtraction (args bounded: no overflow possible;
// underflow = true-zero weight). Q pre-scaled by 0.25*log2e, kk bias folded
// into the MFMA accumulator init.
__global__ __launch_bounds__(256, 2) void attn_dist_kernel(
    const float* __restrict__ Qg, const float* __restrict__ Kg,
    const float* __restrict__ Vg, float* __restrict__ Og)
{
    __shared__ __align__(16) __bf16 sK[TK * SKS];   // [key][d] row-major
    __shared__ __align__(16) __bf16 sV[Dc * 64];    // V^T, xor-swizzled 16B chunks
    __shared__ __align__(16) __bf16 sP[BQ * SPS];   // [q][key]
    __shared__ __align__(16) float  skk[TK];
    __shared__ __align__(16) float  sl[BQ];

    const int tid  = threadIdx.x;
    const int wave = tid >> 6;
    const int lane = tid & 63;
    const int qd   = lane >> 4;   // quad 0..3
    const int c    = lane & 15;

    const int qt = blockIdx.x;    // 0..15
    const int bh = blockIdx.y;    // 0..31
    const size_t base = (size_t)bh * Nc * Dc;
    const float* Qp = Qg + base;
    const float* Kp = Kg + base;
    const float* Vp = Vg + base;

    constexpr float LOG2E = 1.44269504088896340736f;
    const float qscale  = 0.25f  * LOG2E;
    const float kkscale = 0.125f * LOG2E;

    const int i0 = qt * BQ + wave * WQ;

    // Q fragments (B-operand layout): qf[h][ks] = Q[i0+h*16+c][ks*32+qd*8+j]
    bf16x8 qf[2][2];
#pragma unroll
    for (int h = 0; h < 2; ++h) {
        const float* qrow = Qp + (size_t)(i0 + h * 16 + c) * Dc + qd * 8;
#pragma unroll
        for (int ks = 0; ks < 2; ++ks) {
            float4 a = *(const float4*)(qrow + ks * 32);
            float4 b = *(const float4*)(qrow + ks * 32 + 4);
            bf16x8 f;
            f[0] = (__bf16)(a.x * qscale); f[1] = (__bf16)(a.y * qscale);
            f[2] = (__bf16)(a.z * qscale); f[3] = (__bf16)(a.w * qscale);
            f[4] = (__bf16)(b.x * qscale); f[5] = (__bf16)(b.y * qscale);
            f[6] = (__bf16)(b.z * qscale); f[7] = (__bf16)(b.w * qscale);
            qf[h][ks] = f;
        }
    }

    // Staging assignment: thread stages K/V row js, d-cols ds_..ds_+15.
    const int js  = tid >> 2;
    const int ds_ = (tid & 3) * 16;

    float4 kreg[4], vreg[4];
    {
        const float* kr = Kp + (size_t)js * Dc + ds_;
        const float* vr = Vp + (size_t)js * Dc + ds_;
#pragma unroll
        for (int m = 0; m < 4; ++m) {
            kreg[m] = *(const float4*)(kr + m * 4);
            vreg[m] = *(const float4*)(vr + m * 4);
        }
    }

    floatx4 oacc[2][4];
#pragma unroll
    for (int h = 0; h < 2; ++h)
#pragma unroll
        for (int dt = 0; dt < 4; ++dt)
#pragma unroll
            for (int e = 0; e < 4; ++e) oacc[h][dt][e] = 0.f;
    float lp[2] = {0.f, 0.f};

    for (int jt = 0; jt < Nc / TK; ++jt) {
        __syncthreads();   // previous tile fully consumed
        {
            // kk_j (fp32) via 4-lane shuffle tree
            float ss = 0.f;
#pragma unroll
            for (int m = 0; m < 4; ++m)
                ss += kreg[m].x * kreg[m].x + kreg[m].y * kreg[m].y
                    + kreg[m].z * kreg[m].z + kreg[m].w * kreg[m].w;
            ss += __shfl_xor(ss, 1);
            ss += __shfl_xor(ss, 2);
            if ((tid & 3) == 0) skk[js] = ss * kkscale;

            bf16x8 kb0, kb1;
            kb0[0]=(__bf16)kreg[0].x; kb0[1]=(__bf16)kreg[0].y;
            kb0[2]=(__bf16)kreg[0].z; kb0[3]=(__bf16)kreg[0].w;
            kb0[4]=(__bf16)kreg[1].x; kb0[5]=(__bf16)kreg[1].y;
            kb0[6]=(__bf16)kreg[1].z; kb0[7]=(__bf16)kreg[1].w;
            kb1[0]=(__bf16)kreg[2].x; kb1[1]=(__bf16)kreg[2].y;
            kb1[2]=(__bf16)kreg[2].z; kb1[3]=(__bf16)kreg[2].w;
            kb1[4]=(__bf16)kreg[3].x; kb1[5]=(__bf16)kreg[3].y;
            kb1[6]=(__bf16)kreg[3].z; kb1[7]=(__bf16)kreg[3].w;
            *(bf16x8*)&sK[js * SKS + ds_]     = kb0;
            *(bf16x8*)&sK[js * SKS + ds_ + 8] = kb1;

            // V^T swizzled scalar writes: (d, key=js)
            float vv[16];
#pragma unroll
            for (int m = 0; m < 4; ++m) {
                vv[4*m+0] = vreg[m].x; vv[4*m+1] = vreg[m].y;
                vv[4*m+2] = vreg[m].z; vv[4*m+3] = vreg[m].w;
            }
            const int jc = js >> 3, jo = js & 7;
#pragma unroll
            for (int e = 0; e < 16; ++e) {
                const int d = ds_ + e;
                const int f = (d ^ (d >> 3)) & 7;
                sV[d * 64 + ((jc ^ f) << 3) + jo] = (__bf16)vv[e];
            }
        }
        __syncthreads();

        // prefetch next tile into registers (overlaps with compute below)
        if (jt + 1 < Nc / TK) {
            const float* kr = Kp + (size_t)((jt + 1) * TK + js) * Dc + ds_;
            const float* vr = Vp + (size_t)((jt + 1) * TK + js) * Dc + ds_;
#pragma unroll
            for (int m = 0; m < 4; ++m) {
                kreg[m] = *(const float4*)(kr + m * 4);
                vreg[m] = *(const float4*)(vr + m * 4);
            }
        }

        // S^T = K . Q^T, acc initialized to -kk (bias folded in)
        floatx4 st[2][4];
#pragma unroll
        for (int kt = 0; kt < 4; ++kt) {
            floatx4 kkf = *(const floatx4*)&skk[kt * 16 + qd * 4];
#pragma unroll
            for (int r = 0; r < 4; ++r) { st[0][kt][r] = -kkf[r]; st[1][kt][r] = -kkf[r]; }
        }
#pragma unroll
        for (int kt = 0; kt < 4; ++kt)
#pragma unroll
            for (int ks = 0; ks < 2; ++ks) {
                bf16x8 kf = *(const bf16x8*)&sK[(kt * 16 + c) * SKS + ks * 32 + qd * 8];
                st[0][kt] = __builtin_amdgcn_mfma_f32_16x16x32_bf16(kf, qf[0][ks], st[0][kt], 0, 0, 0);
                st[1][kt] = __builtin_amdgcn_mfma_f32_16x16x32_bf16(kf, qf[1][ks], st[1][kt], 0, 0, 0);
            }

        // p = exp2(st); accumulate l; pack to bf16; write sP rows (same-wave)
#pragma unroll
        for (int h = 0; h < 2; ++h) {
            const int prow = wave * WQ + h * 16 + c;
#pragma unroll
            for (int kt = 0; kt < 4; ++kt) {
                float p0 = __builtin_amdgcn_exp2f(st[h][kt][0]);
                float p1 = __builtin_amdgcn_exp2f(st[h][kt][1]);
                float p2 = __builtin_amdgcn_exp2f(st[h][kt][2]);
                float p3 = __builtin_amdgcn_exp2f(st[h][kt][3]);
                lp[h] += (p0 + p1) + (p2 + p3);
                bf16x4 pk;
                pk[0]=(__bf16)p0; pk[1]=(__bf16)p1; pk[2]=(__bf16)p2; pk[3]=(__bf16)p3;
                *(bf16x4*)&sP[prow * SPS + kt * 16 + qd * 4] = pk;
            }
        }

        // read P in A-layout (same-wave rows, lgkmcnt-ordered; no barrier)
        bf16x8 pf[2][2];
#pragma unroll
        for (int h = 0; h < 2; ++h)
#pragma unroll
            for (int ks = 0; ks < 2; ++ks)
                pf[h][ks] = *(const bf16x8*)&sP[(wave * WQ + h * 16 + c) * SPS + ks * 32 + qd * 8];

        // O += P . V
#pragma unroll
        for (int dt = 0; dt < 4; ++dt) {
            const int d = dt * 16 + c;
            const int f = (d ^ (d >> 3)) & 7;
#pragma unroll
            for (int ks = 0; ks < 2; ++ks) {
                bf16x8 vf = *(const bf16x8*)&sV[d * 64 + (((ks * 4 + qd) ^ f) << 3)];
                oacc[0][dt] = __builtin_amdgcn_mfma_f32_16x16x32_bf16(pf[0][ks], vf, oacc[0][dt], 0, 0, 0);
                oacc[1][dt] = __builtin_amdgcn_mfma_f32_16x16x32_bf16(pf[1][ks], vf, oacc[1][dt], 0, 0, 0);
            }
        }
    }

    // Epilogue: l per query via quad butterfly (the only softmax shuffles)
#pragma unroll
    for (int h = 0; h < 2; ++h) {
        float l = lp[h];
        l += __shfl_xor(l, 16);
        l += __shfl_xor(l, 32);
        if (qd == 0) sl[wave * WQ + h * 16 + c] = l;
    }
    const int b = bh >> 3, hh = bh & 7;
#pragma unroll
    for (int h = 0; h < 2; ++h) {
        floatx4 lf = *(const floatx4*)&sl[wave * WQ + h * 16 + qd * 4];
#pragma unroll
        for (int r = 0; r < 4; ++r) {
            const float inv = 1.f / lf[r];
            const int i = i0 + h * 16 + qd * 4 + r;
            float* orow = Og + (((size_t)b * Nc + i) * Hc + hh) * Dc + c;
#pragma unroll
            for (int dt = 0; dt < 4; ++dt)
                orow[dt * 16] = oacc[h][dt][r] * inv;
        }
    }
}

extern "C" void kernel_launch(void* const* d_in, const int* in_sizes, int n_in,
                              void* d_out, int out_size, void* d_ws, size_t ws_size,
                              hipStream_t stream) {
    const float* q = (const float*)d_in[0];
    const float* k = (const float*)d_in[1];
    const float* v = (const float*)d_in[2];
    float* out = (float*)d_out;
    dim3 grid(Nc / BQ, Bc * Hc);
    dim3 block(256);
    attn_dist_kernel<<<grid, block, 0, stream>>>(q, k, v, out);
}

// Round 3
// 140.797 us; speedup vs baseline: 2.1928x; 1.0481x over previous
//
#include <hip/hip_runtime.h>

typedef __bf16 bf16x4 __attribute__((ext_vector_type(4)));
typedef __bf16 bf16x8 __attribute__((ext_vector_type(8)));
typedef float floatx4 __attribute__((ext_vector_type(4)));

constexpr int Bc = 4, Hc = 8, Nc = 2048, Dc = 64;
constexpr int BQ = 128;      // q-rows per block
constexpr int WQ = 32;       // q-rows per wave
constexpr int TK = 64;       // keys per tile
constexpr int NT = Nc / TK;  // 32 tiles
constexpr int SPS = 72;      // sP row stride (bf16)
constexpr float LOG2E = 1.44269504088896340736f;

// ws layout (needs ~17.04 MB):
//   Ksw: [bh][jt] 8 KiB LDS-image, chunk g = key*8 + (kc ^ (key&7)) holds K[key][kc*8..+7] bf16
//   Vsw: [bh][jt] 8 KiB LDS-image, chunk g = d*8   + (kc ^ (d&7))   holds V^T[d][kc*8..+7] bf16
//   kkn: [bh][key] fp32 = -(sum K^2)*0.125*log2e  (softmax bias, pre-negated+scaled)
constexpr size_t KSW_OFF = 0;
constexpr size_t VSW_OFF = (size_t)32 * NT * 8192;            // 8 MiB
constexpr size_t KKN_OFF = VSW_OFF * 2;                       // 16 MiB

typedef __attribute__((address_space(1))) const unsigned int gu32;
typedef __attribute__((address_space(3))) unsigned int lu32;
__device__ __forceinline__ void dma16(const void* g, void* l) {
    __builtin_amdgcn_global_load_lds((gu32*)g, (lu32*)l, 16, 0, 0);
}
__device__ __forceinline__ void dma4(const void* g, void* l) {
    __builtin_amdgcn_global_load_lds((gu32*)g, (lu32*)l, 4, 0, 0);
}

// ---------------- pre-pass: K/V -> swizzled bf16 tile images + kk bias ----------------
__global__ __launch_bounds__(256) void prep_kernel(
    const float* __restrict__ Kg, const float* __restrict__ Vg, char* __restrict__ ws)
{
    __shared__ float sT[64 * 68];   // V tile [key][d], pad 4
    const int tid = threadIdx.x;
    const int jt = blockIdx.x, bh = blockIdx.y;
    const int js = tid >> 2, dc = tid & 3, ds_ = dc * 16;

    __bf16* Ksw = (__bf16*)(ws + KSW_OFF);
    __bf16* Vsw = (__bf16*)(ws + VSW_OFF);
    float*  kkn = (float*)(ws + KKN_OFF);
    const size_t rb = ((size_t)bh * Nc + jt * 64 + js) * Dc + ds_;

    {   // K: convert + kk + swizzled image write
        float4 a0 = *(const float4*)(Kg + rb);
        float4 a1 = *(const float4*)(Kg + rb + 4);
        float4 a2 = *(const float4*)(Kg + rb + 8);
        float4 a3 = *(const float4*)(Kg + rb + 12);
        float ss = a0.x*a0.x + a0.y*a0.y + a0.z*a0.z + a0.w*a0.w
                 + a1.x*a1.x + a1.y*a1.y + a1.z*a1.z + a1.w*a1.w
                 + a2.x*a2.x + a2.y*a2.y + a2.z*a2.z + a2.w*a2.w
                 + a3.x*a3.x + a3.y*a3.y + a3.z*a3.z + a3.w*a3.w;
        ss += __shfl_xor(ss, 1);
        ss += __shfl_xor(ss, 2);
        if (dc == 0) kkn[(size_t)bh * Nc + jt * 64 + js] = -(ss * 0.125f * LOG2E);
        bf16x8 c0, c1;
        c0[0]=(__bf16)a0.x; c0[1]=(__bf16)a0.y; c0[2]=(__bf16)a0.z; c0[3]=(__bf16)a0.w;
        c0[4]=(__bf16)a1.x; c0[5]=(__bf16)a1.y; c0[6]=(__bf16)a1.z; c0[7]=(__bf16)a1.w;
        c1[0]=(__bf16)a2.x; c1[1]=(__bf16)a2.y; c1[2]=(__bf16)a2.z; c1[3]=(__bf16)a2.w;
        c1[4]=(__bf16)a3.x; c1[5]=(__bf16)a3.y; c1[6]=(__bf16)a3.z; c1[7]=(__bf16)a3.w;
        __bf16* tile = Ksw + ((size_t)bh * NT + jt) * 4096;
        *(bf16x8*)(tile + (js * 8 + ((dc * 2    ) ^ (js & 7))) * 8) = c0;
        *(bf16x8*)(tile + (js * 8 + ((dc * 2 + 1) ^ (js & 7))) * 8) = c1;
    }
    {   // V: load coalesced -> LDS
        float4 v0 = *(const float4*)(Vg + rb);
        float4 v1 = *(const float4*)(Vg + rb + 4);
        float4 v2 = *(const float4*)(Vg + rb + 8);
        float4 v3 = *(const float4*)(Vg + rb + 12);
        float* r = &sT[js * 68 + ds_];
        *(float4*)r = v0; *(float4*)(r + 4) = v1;
        *(float4*)(r + 8) = v2; *(float4*)(r + 12) = v3;
    }
    __syncthreads();
    {   // V^T swizzled image write (coalesced: 4 threads/d cover 128B)
        const int d = tid >> 2;
        __bf16* tile = Vsw + ((size_t)bh * NT + jt) * 4096;
#pragma unroll
        for (int e2 = 0; e2 < 2; ++e2) {
            const int kc = (tid & 3) * 2 + e2;
            bf16x8 cc;
#pragma unroll
            for (int e = 0; e < 8; ++e) cc[e] = (__bf16)sT[(kc * 8 + e) * 68 + d];
            *(bf16x8*)(tile + (d * 8 + (kc ^ (d & 7))) * 8) = cc;
        }
    }
}

// ---------------- main fused attention ----------------
// logits*log2e = (2qk - kk)/8*log2e; qq cancels. exp2-domain, no max-sub
// (bounded args). Q pre-scaled 0.25*log2e; -kk*log2e/8 is the acc init.
__global__ __launch_bounds__(256, 2) void attn_kernel(
    const float* __restrict__ Qg, const char* __restrict__ ws, float* __restrict__ Og)
{
    __shared__ __align__(16) __bf16 sK[2][4096];
    __shared__ __align__(16) __bf16 sV[2][4096];
    __shared__ __align__(16) float  skk[2][64];
    __shared__ __align__(16) __bf16 sP[BQ * SPS];
    __shared__ __align__(16) float  sl[BQ];

    const int tid  = threadIdx.x;
    const int wave = tid >> 6;
    const int lane = tid & 63;
    const int qd   = lane >> 4;
    const int c    = lane & 15;

    const int qt = blockIdx.x;    // 0..15
    const int bh = blockIdx.y;    // 0..31

    const char* Kimg = ws + KSW_OFF + (size_t)bh * NT * 8192;
    const char* Vimg = ws + VSW_OFF + (size_t)bh * NT * 8192;
    const float* kkp = (const float*)(ws + KKN_OFF) + (size_t)bh * Nc;

    const float qscale = 0.25f * LOG2E;
    const int i0 = qt * BQ + wave * WQ;

    // Q fragments (B-operand): qf[h][ks] = Q[i0+h*16+c][ks*32+qd*8+j]*qscale
    bf16x8 qf[2][2];
#pragma unroll
    for (int h = 0; h < 2; ++h) {
        const float* qrow = Qg + ((size_t)bh * Nc + i0 + h * 16 + c) * Dc + qd * 8;
#pragma unroll
        for (int ks = 0; ks < 2; ++ks) {
            float4 a = *(const float4*)(qrow + ks * 32);
            float4 b = *(const float4*)(qrow + ks * 32 + 4);
            bf16x8 f;
            f[0] = (__bf16)(a.x * qscale); f[1] = (__bf16)(a.y * qscale);
            f[2] = (__bf16)(a.z * qscale); f[3] = (__bf16)(a.w * qscale);
            f[4] = (__bf16)(b.x * qscale); f[5] = (__bf16)(b.y * qscale);
            f[6] = (__bf16)(b.z * qscale); f[7] = (__bf16)(b.w * qscale);
            qf[h][ks] = f;
        }
    }

    // fragment byte/elem offsets into an 8KiB image (same for sK and sV)
    const int koff0 = c * 64 + ((qd ^ (c & 7)) << 3);         // ks=0
    const int koff1 = c * 64 + (((4 + qd) ^ (c & 7)) << 3);   // ks=1

    floatx4 oacc[2][4];
#pragma unroll
    for (int h = 0; h < 2; ++h)
#pragma unroll
        for (int dt = 0; dt < 4; ++dt)
#pragma unroll
            for (int e = 0; e < 4; ++e) oacc[h][dt][e] = 0.f;
    float lp[2] = {0.f, 0.f};

    // async stage of tile jt into buffer b: pure DMA, no VALU work
    auto stage = [&](int jt, int b) {
        const char* ki = Kimg + (size_t)jt * 8192;
        const char* vi = Vimg + (size_t)jt * 8192;
#pragma unroll
        for (int i = 0; i < 2; ++i) {
            const int off    = wave * 2048 + i * 1024 + lane * 16;
            const int ldsoff = wave * 2048 + i * 1024;
            dma16(ki + off, (char*)&sK[b][0] + ldsoff);
            dma16(vi + off, (char*)&sV[b][0] + ldsoff);
        }
        if (wave == 3) dma4(kkp + jt * 64 + lane, &skk[b][0]);
    };

    stage(0, 0);

    for (int jt = 0; jt < NT; ++jt) {
        const int b = jt & 1;
        __syncthreads();                       // buf b staged; buf b^1 consumed
        if (jt + 1 < NT) stage(jt + 1, b ^ 1); // issue early, drains at next barrier

        // S^T = K.Q^T with acc init = -kk*scale (bias folded in)
        floatx4 st[2][4];
#pragma unroll
        for (int kt = 0; kt < 4; ++kt) {
            floatx4 kkf = *(const floatx4*)&skk[b][kt * 16 + qd * 4];
            st[0][kt] = kkf; st[1][kt] = kkf;
        }
#pragma unroll
        for (int kt = 0; kt < 4; ++kt) {
            const __bf16* kbase = &sK[b][kt * 1024];
            bf16x8 kf0 = *(const bf16x8*)(kbase + koff0);
            bf16x8 kf1 = *(const bf16x8*)(kbase + koff1);
            st[0][kt] = __builtin_amdgcn_mfma_f32_16x16x32_bf16(kf0, qf[0][0], st[0][kt], 0, 0, 0);
            st[0][kt] = __builtin_amdgcn_mfma_f32_16x16x32_bf16(kf1, qf[0][1], st[0][kt], 0, 0, 0);
            st[1][kt] = __builtin_amdgcn_mfma_f32_16x16x32_bf16(kf0, qf[1][0], st[1][kt], 0, 0, 0);
            st[1][kt] = __builtin_amdgcn_mfma_f32_16x16x32_bf16(kf1, qf[1][1], st[1][kt], 0, 0, 0);
        }

        // p = exp2(st); accumulate l; pack bf16; sP round-trip (same-wave rows)
#pragma unroll
        for (int h = 0; h < 2; ++h) {
            const int prow = wave * WQ + h * 16 + c;
#pragma unroll
            for (int kt = 0; kt < 4; ++kt) {
                float p0 = __builtin_amdgcn_exp2f(st[h][kt][0]);
                float p1 = __builtin_amdgcn_exp2f(st[h][kt][1]);
                float p2 = __builtin_amdgcn_exp2f(st[h][kt][2]);
                float p3 = __builtin_amdgcn_exp2f(st[h][kt][3]);
                lp[h] += (p0 + p1) + (p2 + p3);
                bf16x4 pk;
                pk[0] = (__bf16)p0; pk[1] = (__bf16)p1;
                pk[2] = (__bf16)p2; pk[3] = (__bf16)p3;
                *(bf16x4*)&sP[prow * SPS + kt * 16 + qd * 4] = pk;
            }
        }
        bf16x8 pf[2][2];
#pragma unroll
        for (int h = 0; h < 2; ++h)
#pragma unroll
            for (int ks = 0; ks < 2; ++ks)
                pf[h][ks] = *(const bf16x8*)&sP[(wave * WQ + h * 16 + c) * SPS + ks * 32 + qd * 8];

        // O += P.V
#pragma unroll
        for (int dt = 0; dt < 4; ++dt) {
            const __bf16* vbase = &sV[b][dt * 1024];
            bf16x8 vf0 = *(const bf16x8*)(vbase + koff0);
            bf16x8 vf1 = *(const bf16x8*)(vbase + koff1);
            oacc[0][dt] = __builtin_amdgcn_mfma_f32_16x16x32_bf16(pf[0][0], vf0, oacc[0][dt], 0, 0, 0);
            oacc[0][dt] = __builtin_amdgcn_mfma_f32_16x16x32_bf16(pf[0][1], vf1, oacc[0][dt], 0, 0, 0);
            oacc[1][dt] = __builtin_amdgcn_mfma_f32_16x16x32_bf16(pf[1][0], vf0, oacc[1][dt], 0, 0, 0);
            oacc[1][dt] = __builtin_amdgcn_mfma_f32_16x16x32_bf16(pf[1][1], vf1, oacc[1][dt], 0, 0, 0);
        }
    }

    // Epilogue: l via quad butterfly, normalize, store [B,N,H,D]
#pragma unroll
    for (int h = 0; h < 2; ++h) {
        float l = lp[h];
        l += __shfl_xor(l, 16);
        l += __shfl_xor(l, 32);
        if (qd == 0) sl[wave * WQ + h * 16 + c] = l;
    }
    const int b_ = bh >> 3, hh = bh & 7;
#pragma unroll
    for (int h = 0; h < 2; ++h) {
        floatx4 lf = *(const floatx4*)&sl[wave * WQ + h * 16 + qd * 4];
#pragma unroll
        for (int r = 0; r < 4; ++r) {
            const float inv = 1.f / lf[r];
            const int i = i0 + h * 16 + qd * 4 + r;
            float* orow = Og + (((size_t)b_ * Nc + i) * Hc + hh) * Dc + c;
#pragma unroll
            for (int dt = 0; dt < 4; ++dt)
                orow[dt * 16] = oacc[h][dt][r] * inv;
        }
    }
}

extern "C" void kernel_launch(void* const* d_in, const int* in_sizes, int n_in,
                              void* d_out, int out_size, void* d_ws, size_t ws_size,
                              hipStream_t stream) {
    const float* q = (const float*)d_in[0];
    const float* k = (const float*)d_in[1];
    const float* v = (const float*)d_in[2];
    float* out = (float*)d_out;
    char* ws = (char*)d_ws;   // needs ~17.04 MB
    prep_kernel<<<dim3(NT, Bc * Hc), 256, 0, stream>>>(k, v, ws);
    attn_kernel<<<dim3(Nc / BQ, Bc * Hc), 256, 0, stream>>>(q, ws, out);
}

// Round 5
// 140.783 us; speedup vs baseline: 2.1931x; 1.0001x over previous
//
#include <hip/hip_runtime.h>

typedef __bf16 bf16x4 __attribute__((ext_vector_type(4)));
typedef __bf16 bf16x8 __attribute__((ext_vector_type(8)));
typedef float floatx4 __attribute__((ext_vector_type(4)));

constexpr int Bc = 4, Hc = 8, Nc = 2048, Dc = 64;
constexpr int BQ = 128;      // q-rows per block
constexpr int WQ = 32;       // q-rows per wave
constexpr int TK = 64;       // keys per tile
constexpr int NT = Nc / TK;  // 32 tiles
constexpr int SPS = 72;      // sP row stride (bf16)
constexpr float LOG2E = 1.44269504088896340736f;

// ws layout (~17.04 MB):
//   Ksw: [bh][jt] 8 KiB image, chunk g = key*8 + (kc ^ (key&7)) = K[key][kc*8..+7] bf16
//   Vsw: [bh][jt] 8 KiB image, chunk g = d*8   + (kc ^ (d&7))   = V^T[d][kc*8..+7] bf16
//   kkn: [bh][key] fp32 = -(sum K^2)*0.125*log2e
constexpr size_t KSW_OFF = 0;
constexpr size_t VSW_OFF = (size_t)32 * NT * 8192;   // 8 MiB
constexpr size_t KKN_OFF = VSW_OFF * 2;              // 16 MiB

typedef __attribute__((address_space(1))) const unsigned int gu32;
typedef __attribute__((address_space(3))) unsigned int lu32;
__device__ __forceinline__ void dma16(const void* g, void* l) {
    __builtin_amdgcn_global_load_lds((gu32*)g, (lu32*)l, 16, 0, 0);
}
__device__ __forceinline__ void dma4(const void* g, void* l) {
    __builtin_amdgcn_global_load_lds((gu32*)g, (lu32*)l, 4, 0, 0);
}

// ---------------- prep v2: fully-coalesced image builder ----------------
__global__ __launch_bounds__(256) void prep_kernel(
    const float* __restrict__ Kg, const float* __restrict__ Vg, char* __restrict__ ws)
{
    __shared__ float sT[64 * 68];   // V tile [key][d], stride 68
    const int tid = threadIdx.x;
    const int jt = blockIdx.x, bh = blockIdx.y;

    __bf16* Ksw = (__bf16*)(ws + KSW_OFF) + ((size_t)bh * NT + jt) * 4096;
    __bf16* Vsw = (__bf16*)(ws + VSW_OFF) + ((size_t)bh * NT + jt) * 4096;
    float*  kkn = (float*)(ws + KKN_OFF) + (size_t)bh * Nc + jt * 64;
    const size_t tb = ((size_t)bh * Nc + jt * 64) * Dc;  // tile base (elems)

    // K: thread g handles image chunk g (global read permuted-within-row =>
    // coalesced; image write at g*16B => perfectly coalesced). kk via 8-lane tree.
#pragma unroll
    for (int cc = 0; cc < 2; ++cc) {
        const int g   = tid + cc * 256;
        const int key = g >> 3, kcx = g & 7;
        const int kc  = kcx ^ (key & 7);
        const float* src = Kg + tb + key * 64 + kc * 8;
        float4 a = *(const float4*)src;
        float4 b = *(const float4*)(src + 4);
        float ss = a.x*a.x + a.y*a.y + a.z*a.z + a.w*a.w
                 + b.x*b.x + b.y*b.y + b.z*b.z + b.w*b.w;
        ss += __shfl_xor(ss, 1);
        ss += __shfl_xor(ss, 2);
        ss += __shfl_xor(ss, 4);
        if (kcx == 0) kkn[key] = -(ss * 0.125f * LOG2E);
        bf16x8 c8;
        c8[0]=(__bf16)a.x; c8[1]=(__bf16)a.y; c8[2]=(__bf16)a.z; c8[3]=(__bf16)a.w;
        c8[4]=(__bf16)b.x; c8[5]=(__bf16)b.y; c8[6]=(__bf16)b.z; c8[7]=(__bf16)b.w;
        *(bf16x8*)(Ksw + g * 8) = c8;
    }

    // V: coalesced load -> LDS
    {
        const int js = tid >> 2, dc = (tid & 3) * 16;
        const float* vr = Vg + tb + js * 64 + dc;
        float* dst = &sT[js * 68 + dc];
        *(float4*)dst       = *(const float4*)vr;
        *(float4*)(dst + 4) = *(const float4*)(vr + 4);
        *(float4*)(dst + 8) = *(const float4*)(vr + 8);
        *(float4*)(dst + 12)= *(const float4*)(vr + 12);
    }
    __syncthreads();

    // V^T: thread g builds chunk g; lane-staggered gather order -> low-conflict;
    // global write at g*16B coalesced.
#pragma unroll
    for (int cc = 0; cc < 2; ++cc) {
        const int g = tid + cc * 256;
        const int d = g >> 3, kcx = g & 7;
        const int kc = kcx ^ (d & 7);
        bf16x8 c8;
#pragma unroll
        for (int e = 0; e < 8; ++e) {
            const int ee = (e + kcx) & 7;            // stagger banks across lanes
            c8[ee] = (__bf16)sT[(kc * 8 + ee) * 68 + d];
        }
        *(bf16x8*)(Vsw + g * 8) = c8;
    }
}

// ---------------- main fused attention (round-3 verified version) ----------------
// logits*log2e = (2qk - kk)/8*log2e; qq cancels. exp2-domain, no max-sub
// (bounded args). Q pre-scaled 0.25*log2e; -kk*log2e/8 is the acc init.
__global__ __launch_bounds__(256, 2) void attn_kernel(
    const float* __restrict__ Qg, const char* __restrict__ ws, float* __restrict__ Og)
{
    __shared__ __align__(16) __bf16 sK[2][4096];
    __shared__ __align__(16) __bf16 sV[2][4096];
    __shared__ __align__(16) float  skk[2][64];
    __shared__ __align__(16) __bf16 sP[BQ * SPS];
    __shared__ __align__(16) float  sl[BQ];

    const int tid  = threadIdx.x;
    const int wave = tid >> 6;
    const int lane = tid & 63;
    const int qd   = lane >> 4;
    const int c    = lane & 15;

    const int qt = blockIdx.x;    // 0..15
    const int bh = blockIdx.y;    // 0..31

    const char* Kimg = ws + KSW_OFF + (size_t)bh * NT * 8192;
    const char* Vimg = ws + VSW_OFF + (size_t)bh * NT * 8192;
    const float* kkp = (const float*)(ws + KKN_OFF) + (size_t)bh * Nc;

    const float qscale = 0.25f * LOG2E;
    const int i0 = qt * BQ + wave * WQ;

    // Q fragments (B-operand): qf[h][ks] = Q[i0+h*16+c][ks*32+qd*8+j]*qscale
    bf16x8 qf[2][2];
#pragma unroll
    for (int h = 0; h < 2; ++h) {
        const float* qrow = Qg + ((size_t)bh * Nc + i0 + h * 16 + c) * Dc + qd * 8;
#pragma unroll
        for (int ks = 0; ks < 2; ++ks) {
            float4 a = *(const float4*)(qrow + ks * 32);
            float4 b = *(const float4*)(qrow + ks * 32 + 4);
            bf16x8 f;
            f[0] = (__bf16)(a.x * qscale); f[1] = (__bf16)(a.y * qscale);
            f[2] = (__bf16)(a.z * qscale); f[3] = (__bf16)(a.w * qscale);
            f[4] = (__bf16)(b.x * qscale); f[5] = (__bf16)(b.y * qscale);
            f[6] = (__bf16)(b.z * qscale); f[7] = (__bf16)(b.w * qscale);
            qf[h][ks] = f;
        }
    }

    // fragment elem offsets into an 8KiB image (same for sK and sV)
    const int koff0 = c * 64 + ((qd ^ (c & 7)) << 3);         // ks=0
    const int koff1 = c * 64 + (((4 + qd) ^ (c & 7)) << 3);   // ks=1

    floatx4 oacc[2][4];
#pragma unroll
    for (int h = 0; h < 2; ++h)
#pragma unroll
        for (int dt = 0; dt < 4; ++dt)
#pragma unroll
            for (int e = 0; e < 4; ++e) oacc[h][dt][e] = 0.f;
    float lp[2] = {0.f, 0.f};

    // async stage of tile jt into buffer b: pure DMA, no VALU work
    auto stage = [&](int jt2, int b) {
        const char* ki = Kimg + (size_t)jt2 * 8192;
        const char* vi = Vimg + (size_t)jt2 * 8192;
#pragma unroll
        for (int i = 0; i < 2; ++i) {
            const int off    = wave * 2048 + i * 1024 + lane * 16;
            const int ldsoff = wave * 2048 + i * 1024;
            dma16(ki + off, (char*)&sK[b][0] + ldsoff);
            dma16(vi + off, (char*)&sV[b][0] + ldsoff);
        }
        if (wave == 3) dma4(kkp + jt2 * 64 + lane, &skk[b][0]);
    };

    stage(0, 0);

    for (int jt = 0; jt < NT; ++jt) {
        const int b = jt & 1;
        __syncthreads();                       // buf b staged; buf b^1 consumed
        if (jt + 1 < NT) stage(jt + 1, b ^ 1); // drains at next barrier

        // S^T = K.Q^T with acc init = -kk*scale (bias folded in)
        floatx4 st[2][4];
#pragma unroll
        for (int kt = 0; kt < 4; ++kt) {
            floatx4 kkf = *(const floatx4*)&skk[b][kt * 16 + qd * 4];
            st[0][kt] = kkf; st[1][kt] = kkf;
        }
#pragma unroll
        for (int kt = 0; kt < 4; ++kt) {
            const __bf16* kbase = &sK[b][kt * 1024];
            bf16x8 kf0 = *(const bf16x8*)(kbase + koff0);
            bf16x8 kf1 = *(const bf16x8*)(kbase + koff1);
            st[0][kt] = __builtin_amdgcn_mfma_f32_16x16x32_bf16(kf0, qf[0][0], st[0][kt], 0, 0, 0);
            st[0][kt] = __builtin_amdgcn_mfma_f32_16x16x32_bf16(kf1, qf[0][1], st[0][kt], 0, 0, 0);
            st[1][kt] = __builtin_amdgcn_mfma_f32_16x16x32_bf16(kf0, qf[1][0], st[1][kt], 0, 0, 0);
            st[1][kt] = __builtin_amdgcn_mfma_f32_16x16x32_bf16(kf1, qf[1][1], st[1][kt], 0, 0, 0);
        }

        // p = exp2(st); accumulate l; pack bf16; sP round-trip (same-wave rows)
#pragma unroll
        for (int h = 0; h < 2; ++h) {
            const int prow = wave * WQ + h * 16 + c;
#pragma unroll
            for (int kt = 0; kt < 4; ++kt) {
                float p0 = __builtin_amdgcn_exp2f(st[h][kt][0]);
                float p1 = __builtin_amdgcn_exp2f(st[h][kt][1]);
                float p2 = __builtin_amdgcn_exp2f(st[h][kt][2]);
                float p3 = __builtin_amdgcn_exp2f(st[h][kt][3]);
                lp[h] += (p0 + p1) + (p2 + p3);
                bf16x4 pk;
                pk[0] = (__bf16)p0; pk[1] = (__bf16)p1;
                pk[2] = (__bf16)p2; pk[3] = (__bf16)p3;
                *(bf16x4*)&sP[prow * SPS + kt * 16 + qd * 4] = pk;
            }
        }
        bf16x8 pf[2][2];
#pragma unroll
        for (int h = 0; h < 2; ++h)
#pragma unroll
            for (int ks = 0; ks < 2; ++ks)
                pf[h][ks] = *(const bf16x8*)&sP[(wave * WQ + h * 16 + c) * SPS + ks * 32 + qd * 8];

        // O += P.V
#pragma unroll
        for (int dt = 0; dt < 4; ++dt) {
            const __bf16* vbase = &sV[b][dt * 1024];
            bf16x8 vf0 = *(const bf16x8*)(vbase + koff0);
            bf16x8 vf1 = *(const bf16x8*)(vbase + koff1);
            oacc[0][dt] = __builtin_amdgcn_mfma_f32_16x16x32_bf16(pf[0][0], vf0, oacc[0][dt], 0, 0, 0);
            oacc[0][dt] = __builtin_amdgcn_mfma_f32_16x16x32_bf16(pf[0][1], vf1, oacc[0][dt], 0, 0, 0);
            oacc[1][dt] = __builtin_amdgcn_mfma_f32_16x16x32_bf16(pf[1][0], vf0, oacc[1][dt], 0, 0, 0);
            oacc[1][dt] = __builtin_amdgcn_mfma_f32_16x16x32_bf16(pf[1][1], vf1, oacc[1][dt], 0, 0, 0);
        }
    }

    // Epilogue: l via quad butterfly, normalize, store [B,N,H,D]
#pragma unroll
    for (int h = 0; h < 2; ++h) {
        float l = lp[h];
        l += __shfl_xor(l, 16);
        l += __shfl_xor(l, 32);
        if (qd == 0) sl[wave * WQ + h * 16 + c] = l;
    }
    const int b_ = bh >> 3, hh = bh & 7;
#pragma unroll
    for (int h = 0; h < 2; ++h) {
        floatx4 lf = *(const floatx4*)&sl[wave * WQ + h * 16 + qd * 4];
#pragma unroll
        for (int r = 0; r < 4; ++r) {
            const float inv = 1.f / lf[r];
            const int i = i0 + h * 16 + qd * 4 + r;
            float* orow = Og + (((size_t)b_ * Nc + i) * Hc + hh) * Dc + c;
#pragma unroll
            for (int dt = 0; dt < 4; ++dt)
                orow[dt * 16] = oacc[h][dt][r] * inv;
        }
    }
}

extern "C" void kernel_launch(void* const* d_in, const int* in_sizes, int n_in,
                              void* d_out, int out_size, void* d_ws, size_t ws_size,
                              hipStream_t stream) {
    const float* q = (const float*)d_in[0];
    const float* k = (const float*)d_in[1];
    const float* v = (const float*)d_in[2];
    float* out = (float*)d_out;
    char* ws = (char*)d_ws;   // ~17.04 MB
    prep_kernel<<<dim3(NT, Bc * Hc), 256, 0, stream>>>(k, v, ws);
    attn_kernel<<<dim3(Nc / BQ, Bc * Hc), 256, 0, stream>>>(q, ws, out);
}